// Round 4
// baseline (103.510 us; speedup 1.0000x reference)
//
#include <hip/hip_runtime.h>

#define DIM   1024
#define LPR   64            // whole wave cooperates on one row
#define SEG   (DIM / LPR)   // 16 floats per lane
#define SEG4  (SEG / 4)     // 4 float4 per lane
#define ROWS_PER_BLOCK 4    // 256 threads / 64
#define WAVES_PER_BLOCK 4

typedef float f32x4 __attribute__((ext_vector_type(4)));

// Row recurrence (Givens sweep): carry = value of column s entering step s.
//   out[s]  = c_s*carry - s_s*v[s+1]
//   carry'  = s_s*carry + c_s*v[s+1]
// Affine in carry -> per-lane (A,B) over its 16 steps + 6-step shfl scan.
//
// All global traffic is coalesced 1KB/instr. Wave's row (4KB) staged to LDS
// via global_load_lds: linear LDS dest + XOR-involution p(L)=L^((L>>3)&3)
// applied to BOTH the global source lane offset and the ds_read/ds_write
// index (guide rule 21), giving bank-balanced (minimum-cycle) b128 access.
__global__ __launch_bounds__(256, 6)
void qll_kernel(const float* __restrict__ x,
                const float* __restrict__ angles,
                float* __restrict__ out,
                int batch)
{
    // cs transposed so the phase-loop read is cs[i*64 + lane]:
    //   step j lives at loc = ((j&15)<<6) | (j>>4); fill iterates loc linearly
    //   (consecutive lanes -> consecutive banks, conflict-free write).
    __shared__ float2 cs[DIM];                      // 8 KB
    __shared__ f32x4  stage[WAVES_PER_BLOCK][256];  // 16 KB, wave-private row

    for (int loc = threadIdx.x; loc < DIM; loc += blockDim.x) {
        int j = ((loc & 63) << 4) | (loc >> 6);     // inverse of loc(j)
        float a = angles[j];
        cs[loc] = make_float2(cosf(a), sinf(a));
    }
    __syncthreads();

    const int tid  = threadIdx.x;
    const int l    = tid & 63;        // lane = segment index within row
    const int wv   = tid >> 6;        // wave 0..3
    const int r0   = blockIdx.x * ROWS_PER_BLOCK + wv;
    if (r0 >= batch) return;          // wave-uniform

    const int swz_l = l ^ ((l >> 3) & 3);   // involution on float4 index low bits

    // ---- stage the row (4 KB) into LDS, coalesced, pre-swizzled source ----
    const f32x4* gin = reinterpret_cast<const f32x4*>(x) + (size_t)r0 * 256;
#pragma unroll
    for (int m = 0; m < SEG4; ++m) {
        __builtin_amdgcn_global_load_lds(
            (const __attribute__((address_space(1))) void*)(gin + m * 64 + swz_l),
            (__attribute__((address_space(3))) void*)(&stage[wv][m * 64]),
            16, 0, 0);
    }
    asm volatile("s_waitcnt vmcnt(0)" ::: "memory");
    __builtin_amdgcn_sched_barrier(0);

    // ---- read this lane's 16-float segment (bank-balanced b128s) ----
    float v[SEG];
#pragma unroll
    for (int e = 0; e < SEG4; ++e) {
        f32x4 q = stage[wv][l * 4 + (e ^ ((l >> 1) & 3))];
        v[4*e+0] = q.x; v[4*e+1] = q.y; v[4*e+2] = q.z; v[4*e+3] = q.w;
    }

    // boundary exchanges (capture BEFORE phase 2 overwrites v[])
    float v0row = __shfl(v[0], 0);        // row's original column 0
    float v1row = __shfl(v[1], 0);
    float vnext = __shfl_down(v[0], 1);   // next lane's first elem (lane 63: unused)

    // ---- phase 1: per-lane affine (A,B) with carry_in = 0 ----
    float A = 1.f, B = 0.f;
#pragma unroll
    for (int i = 0; i < SEG - 1; ++i) {
        float2 w = cs[i * LPR + l];
        B = w.y * B + w.x * v[i + 1];
        A = w.y * A;
    }
    {   // last step of segment consumes the boundary element
        float2 w = cs[(SEG - 1) * LPR + l];
        B = w.y * B + w.x * vnext;        // lane 63: finite garbage, unused
        A = w.y * A;
    }

    // ---- inclusive affine scan across 64 lanes ----
#pragma unroll
    for (int d = 1; d < LPR; d <<= 1) {
        float pa = __shfl_up(A, d);
        float pb = __shfl_up(B, d);
        if (l >= d) { B = A * pb + B; A = A * pa; }
    }
    // exclusive prefix -> carry entering this lane's segment
    float ea = __shfl_up(A, 1);
    float eb = __shfl_up(B, 1);
    if (l == 0) { ea = 1.f; eb = 0.f; }
    float carry = ea * v0row + eb;

    // provisional out[0] (result of step 0), consumed by the wrap step 1023
    float2 w0 = cs[0];                    // step 0 lives at loc 0; broadcast
    float out0_prov = w0.x * v0row - w0.y * v1row;

    // ---- phase 2: replay with true carry, outputs into v[] ----
#pragma unroll
    for (int i = 0; i < SEG - 1; ++i) {
        float2 w = cs[i * LPR + l];
        float vn = v[i + 1];
        float o  = w.x * carry - w.y * vn;
        carry    = w.y * carry + w.x * vn;
        v[i] = o;
    }
    {   // last step; lane 63 executes the wrap step 1023 against out[0]
        float2 w  = cs[(SEG - 1) * LPR + l];
        float vn  = (l == LPR - 1) ? out0_prov : vnext;
        float o   = w.x * carry - w.y * vn;
        float nc  = w.y * carry + w.x * vn;
        v[SEG - 1] = o;
        float out0_final = __shfl(nc, LPR - 1);   // lane 63 -> all
        if (l == 0) v[0] = out0_final;
    }

    // ---- out-stage into same buffer (same-wave DS pipe is in-order; the
    //      earlier reads complete before these writes retire), then
    //      coalesced nontemporal stores ----
#pragma unroll
    for (int e = 0; e < SEG4; ++e) {
        f32x4 q = { v[4*e+0], v[4*e+1], v[4*e+2], v[4*e+3] };
        stage[wv][l * 4 + (e ^ ((l >> 1) & 3))] = q;
    }
    f32x4* gout = reinterpret_cast<f32x4*>(out) + (size_t)r0 * 256;
#pragma unroll
    for (int m = 0; m < SEG4; ++m) {
        f32x4 q = stage[wv][m * 64 + swz_l];
        __builtin_nontemporal_store(q, gout + m * 64 + l);
    }
}

extern "C" void kernel_launch(void* const* d_in, const int* in_sizes, int n_in,
                              void* d_out, int out_size, void* d_ws, size_t ws_size,
                              hipStream_t stream) {
    const float* x      = (const float*)d_in[0];
    const float* angles = (const float*)d_in[1];
    float* outp         = (float*)d_out;

    int batch = in_sizes[0] / DIM;                              // 65536
    int grid  = (batch + ROWS_PER_BLOCK - 1) / ROWS_PER_BLOCK;  // 16384
    qll_kernel<<<grid, 256, 0, stream>>>(x, angles, outp, batch);
}